// Round 2
// baseline (678.688 us; speedup 1.0000x reference)
//
#include <hip/hip_runtime.h>
#include <math.h>

#define N_ROWS 131072
#define DIMS 64
#define K_CODES 512

// ---------------- K0: zero ws counters + c2 via numpy-pairwise (bitwise) --------
__global__ __launch_bounds__(256) void vq_init(const float* __restrict__ codebook,
                                               double* __restrict__ loss_sum,
                                               int* __restrict__ bins,
                                               float* __restrict__ c2g) {
  #pragma clang fp contract(off)
  const int t = threadIdx.x;
  if (t == 0) *loss_sum = 0.0;
  for (int b = t; b < K_CODES; b += 256) bins[b] = 0;
  // numpy pairwise_sum, n=64: 8 accumulators over stride-8 lanes, then fixed tree.
  for (int k = t; k < K_CODES; k += 256) {
    const float* cr = codebook + k * DIMS;
    float r[8];
    #pragma unroll
    for (int j = 0; j < 8; ++j) r[j] = cr[j] * cr[j];
    for (int i = 8; i < 64; i += 8) {
      #pragma unroll
      for (int j = 0; j < 8; ++j) r[j] += cr[i + j] * cr[i + j];  // contract OFF: mul, then add
    }
    c2g[k] = ((r[0] + r[1]) + (r[2] + r[3])) + ((r[4] + r[5]) + (r[6] + r[7]));
  }
}

// ---------------- K1: np-bitwise scores + first-index argmin ----------------
// WG: 256 threads, 128 rows x 512 codes (4 chunks of 128 codes).
// Thread (cg=t&15, rg=t>>4) owns rows rg*8..rg*8+7, codes c*128 + cg*8..+7.
// M[n,k] = sequential fmaf over d (BLAS sgemm order); d2 = (x2 - 2*M) + c2, each op fp32.
__global__ __launch_bounds__(256, 2) void vq_argmin(const float* __restrict__ latents,
                                                    const float* __restrict__ codebook,
                                                    const float* __restrict__ c2g,
                                                    float* __restrict__ out_codes) {
  #pragma clang fp contract(off)
  __shared__ float xt[128 * 64];   // latent tile, row-major
  __shared__ float cbT[64 * 128];  // codebook chunk, [d][k]
  __shared__ float x2s[128];
  __shared__ float c2s[K_CODES];
  const int t = threadIdx.x;
  const int rowbase = blockIdx.x * 128;

  // stage x tile (coalesced float4) + c2
  {
    const float4* src = (const float4*)(latents + (size_t)rowbase * DIMS);
    float4* dst = (float4*)xt;
    #pragma unroll
    for (int p = 0; p < 8; ++p) dst[p * 256 + t] = src[p * 256 + t];
    c2s[t] = c2g[t];
    c2s[256 + t] = c2g[256 + t];
  }
  __syncthreads();

  // x2 per row: numpy pairwise_sum, exact replication via lane shuffles.
  // a_d = fl(x_d^2); r_j = ((a_j + a_{j+8}) + a_{j+16}) ... + a_{j+56};
  // x2 = ((r0+r1)+(r2+r3))+((r4+r5)+(r6+r7)).
  {
    const int lane = t & 63;
    const int wv = t >> 6;  // 4 waves, 32 rows each
    for (int rr = 0; rr < 32; ++rr) {
      const int row = wv * 32 + rr;
      const float v = xt[row * 64 + lane];
      const float a = v * v;             // contract OFF: exact fp32 square
      float s = a;
      #pragma unroll
      for (int k8 = 1; k8 < 8; ++k8) s += __shfl(a, lane + 8 * k8);  // ascending d order
      const float r0 = __shfl(s, 0), r1 = __shfl(s, 1), r2 = __shfl(s, 2), r3 = __shfl(s, 3);
      const float r4 = __shfl(s, 4), r5 = __shfl(s, 5), r6 = __shfl(s, 6), r7 = __shfl(s, 7);
      if (lane == 0) x2s[row] = ((r0 + r1) + (r2 + r3)) + ((r4 + r5) + (r6 + r7));
    }
  }
  __syncthreads();

  const int cg = t & 15;
  const int rg = t >> 4;

  float x2v[8];
  #pragma unroll
  for (int i = 0; i < 8; ++i) x2v[i] = x2s[rg * 8 + i];

  float m1[8]; int i1[8];
  #pragma unroll
  for (int i = 0; i < 8; ++i) { m1[i] = __builtin_inff(); i1[i] = 0x7fffffff; }

  for (int c = 0; c < 4; ++c) {
    __syncthreads();  // protect cbT from overwrite while previous consumers read
    // stage codebook chunk transposed: cbT[d][k]; conflict-free LDS writes
    const float* cbsrc = codebook + c * 128 * DIMS;
    #pragma unroll
    for (int p = 0; p < 8; ++p) {
      int f = p * 256 + t;     // 0..2047
      int d4 = f >> 7;         // 0..15
      int kk = f & 127;        // 0..127
      float4 v = *(const float4*)(cbsrc + kk * DIMS + d4 * 4);
      cbT[(d4 * 4 + 0) * 128 + kk] = v.x;
      cbT[(d4 * 4 + 1) * 128 + kk] = v.y;
      cbT[(d4 * 4 + 2) * 128 + kk] = v.z;
      cbT[(d4 * 4 + 3) * 128 + kk] = v.w;
    }
    __syncthreads();

    float acc[8][8];
    #pragma unroll
    for (int i = 0; i < 8; ++i)
      #pragma unroll
      for (int j = 0; j < 8; ++j) acc[i][j] = 0.f;

    const float* xrow = xt + (rg * 8) * DIMS;
    for (int d4 = 0; d4 < DIMS; d4 += 4) {
      float xv[8][4];
      #pragma unroll
      for (int i = 0; i < 8; ++i)
        *(float4*)&xv[i][0] = *(const float4*)&xrow[i * DIMS + d4];
      #pragma unroll
      for (int dd = 0; dd < 4; ++dd) {  // d strictly ascending: single fmaf chain per (i,j)
        float cv[8];
        *(float4*)&cv[0] = *(const float4*)&cbT[(d4 + dd) * 128 + cg * 8];
        *(float4*)&cv[4] = *(const float4*)&cbT[(d4 + dd) * 128 + cg * 8 + 4];
        #pragma unroll
        for (int i = 0; i < 8; ++i) {
          const float xs = xv[i][dd];
          #pragma unroll
          for (int j = 0; j < 8; ++j) acc[i][j] = fmaf(xs, cv[j], acc[i][j]);
        }
      }
    }

    // d2 = (x2 - 2*M) + c2, each op one fp32 rounding (2*M exact).
    float c2l[8];
    *(float4*)&c2l[0] = *(const float4*)&c2s[c * 128 + cg * 8];
    *(float4*)&c2l[4] = *(const float4*)&c2s[c * 128 + cg * 8 + 4];
    #pragma unroll
    for (int j = 0; j < 8; ++j) {
      const int k = c * 128 + cg * 8 + j;  // ascending k within thread across (c,j)
      const float c2v = c2l[j];
      #pragma unroll
      for (int i = 0; i < 8; ++i) {
        const float tt = x2v[i] - 2.0f * acc[i][j];
        const float s = tt + c2v;
        if (s < m1[i]) { m1[i] = s; i1[i] = k; }  // strict < keeps first index
      }
    }
  }

  // cross-thread merge over cg (16 lanes, contiguous in wave): min value, tie -> min index
  #pragma unroll
  for (int i = 0; i < 8; ++i) {
    float v = m1[i]; int idx = i1[i];
    #pragma unroll
    for (int off = 1; off < 16; off <<= 1) {
      const float ov = __shfl_xor(v, off);
      const int oi = __shfl_xor(idx, off);
      if (ov < v || (ov == v && oi < idx)) { v = ov; idx = oi; }
    }
    if (cg == 0) out_codes[rowbase + rg * 8 + i] = (float)idx;
  }
}

// ---------------- K2: gather + STE output + loss sum + histogram ----------------
__global__ __launch_bounds__(256) void vq_outputs(const float* __restrict__ latents,
                                                  const float* __restrict__ codebook,
                                                  const float* __restrict__ out_codes,
                                                  float* __restrict__ out_st,
                                                  int* __restrict__ bins,
                                                  double* __restrict__ loss_sum) {
  #pragma clang fp contract(off)
  const int t = threadIdx.x;
  const size_t e = (size_t)blockIdx.x * 256 + t;
  const int row = (int)(e >> 6);
  const int d = (int)(e & 63);
  const int k = (int)out_codes[row];
  const float l = latents[e];
  const float q = codebook[k * DIMS + d];
  out_st[e] = l + (q - l);            // straight-through, np rounding order
  const float diff = l - q;
  double v = (double)(diff * diff);
  #pragma unroll
  for (int off = 32; off > 0; off >>= 1) v += __shfl_down(v, off);
  __shared__ double wsum[4];
  if ((t & 63) == 0) wsum[t >> 6] = v;
  __syncthreads();
  if (t == 0) atomicAdd(loss_sum, wsum[0] + wsum[1] + wsum[2] + wsum[3]);
  if (d == 0) atomicAdd(&bins[k], 1);
}

// ---------------- K3: perplexity + scalar outputs ----------------
__global__ __launch_bounds__(512) void vq_finalize(const int* __restrict__ bins,
                                                   const double* __restrict__ loss_sum,
                                                   float* __restrict__ out3) {
  __shared__ double red[512];
  const int t = threadIdx.x;
  const double p = (double)bins[t] / 131072.0;
  red[t] = -p * log(p + 1e-10);
  __syncthreads();
  for (int s = 256; s > 0; s >>= 1) {
    if (t < s) red[t] += red[t + s];
    __syncthreads();
  }
  if (t == 0) {
    const double mean = *loss_sum / 8388608.0;
    out3[0] = (float)(0.25 * mean);  // commitment * COMMITMENT_COST
    out3[1] = (float)mean;           // codebook_loss (same squares bitwise)
    out3[2] = (float)exp(red[0]);    // perplexity
  }
}

extern "C" void kernel_launch(void* const* d_in, const int* in_sizes, int n_in,
                              void* d_out, int out_size, void* d_ws, size_t ws_size,
                              hipStream_t stream) {
  const float* latents = (const float*)d_in[0];
  const float* codebook = (const float*)d_in[1];

  float* out = (float*)d_out;
  float* out_st = out;                                   // 8388608
  float* out_codes = out + (size_t)N_ROWS * DIMS;        // 131072 (codes as float)
  float* out3 = out_codes + N_ROWS;                      // 3 scalars

  char* ws = (char*)d_ws;
  double* loss_sum = (double*)ws;                // [0,8)
  int* bins = (int*)(ws + 8);                    // [8, 2056)
  float* c2g = (float*)(ws + 8 + 2048);          // [2056, 4104)

  hipLaunchKernelGGL(vq_init, dim3(1), dim3(256), 0, stream,
                     codebook, loss_sum, bins, c2g);
  hipLaunchKernelGGL(vq_argmin, dim3(N_ROWS / 128), dim3(256), 0, stream,
                     latents, codebook, c2g, out_codes);
  hipLaunchKernelGGL(vq_outputs, dim3(N_ROWS * DIMS / 256), dim3(256), 0, stream,
                     latents, codebook, out_codes, out_st, bins, loss_sum);
  hipLaunchKernelGGL(vq_finalize, dim3(1), dim3(512), 0, stream,
                     bins, loss_sum, out3);
}

// Round 3
// 243.402 us; speedup vs baseline: 2.7883x; 2.7883x over previous
//
#include <hip/hip_runtime.h>
#include <math.h>

#define N_ROWS 131072
#define DIMS 64
#define K_CODES 512
#define OUT_BLOCKS 1024

// ---------------- K0: zero bins + c2 via numpy-pairwise (bitwise) --------
__global__ __launch_bounds__(256) void vq_init(const float* __restrict__ codebook,
                                               int* __restrict__ bins,
                                               float* __restrict__ c2g) {
  #pragma clang fp contract(off)
  const int t = threadIdx.x;
  for (int b = t; b < K_CODES; b += 256) bins[b] = 0;
  // numpy pairwise_sum, n=64: 8 accumulators over stride-8 lanes, then fixed tree.
  for (int k = t; k < K_CODES; k += 256) {
    const float* cr = codebook + k * DIMS;
    float r[8];
    #pragma unroll
    for (int j = 0; j < 8; ++j) r[j] = cr[j] * cr[j];
    for (int i = 8; i < 64; i += 8) {
      #pragma unroll
      for (int j = 0; j < 8; ++j) r[j] += cr[i + j] * cr[i + j];  // contract OFF: mul, then add
    }
    c2g[k] = ((r[0] + r[1]) + (r[2] + r[3])) + ((r[4] + r[5]) + (r[6] + r[7]));
  }
}

// ---------------- K1: np-bitwise scores + first-index argmin (+ histogram) -------
// WG: 256 threads, 128 rows x 512 codes (4 chunks of 128 codes).
// Thread (cg=t&15, rg=t>>4) owns rows rg*8..rg*8+7, codes c*128 + cg*8..+7.
// M[n,k] = sequential fmaf over d (BLAS sgemm order); d2 = (x2 - 2*M) + c2, each op fp32.
__global__ __launch_bounds__(256, 2) void vq_argmin(const float* __restrict__ latents,
                                                    const float* __restrict__ codebook,
                                                    const float* __restrict__ c2g,
                                                    float* __restrict__ out_codes,
                                                    int* __restrict__ bins) {
  #pragma clang fp contract(off)
  __shared__ float xt[128 * 64];   // latent tile, row-major
  __shared__ float cbT[64 * 128];  // codebook chunk, [d][k]
  __shared__ float x2s[128];
  __shared__ float c2s[K_CODES];
  const int t = threadIdx.x;
  const int rowbase = blockIdx.x * 128;

  // stage x tile (coalesced float4) + c2
  {
    const float4* src = (const float4*)(latents + (size_t)rowbase * DIMS);
    float4* dst = (float4*)xt;
    #pragma unroll
    for (int p = 0; p < 8; ++p) dst[p * 256 + t] = src[p * 256 + t];
    c2s[t] = c2g[t];
    c2s[256 + t] = c2g[256 + t];
  }
  __syncthreads();

  // x2 per row: numpy pairwise_sum, exact replication via lane shuffles.
  {
    const int lane = t & 63;
    const int wv = t >> 6;  // 4 waves, 32 rows each
    for (int rr = 0; rr < 32; ++rr) {
      const int row = wv * 32 + rr;
      const float v = xt[row * 64 + lane];
      const float a = v * v;             // contract OFF: exact fp32 square
      float s = a;
      #pragma unroll
      for (int k8 = 1; k8 < 8; ++k8) s += __shfl(a, lane + 8 * k8);  // ascending d order
      const float r0 = __shfl(s, 0), r1 = __shfl(s, 1), r2 = __shfl(s, 2), r3 = __shfl(s, 3);
      const float r4 = __shfl(s, 4), r5 = __shfl(s, 5), r6 = __shfl(s, 6), r7 = __shfl(s, 7);
      if (lane == 0) x2s[row] = ((r0 + r1) + (r2 + r3)) + ((r4 + r5) + (r6 + r7));
    }
  }
  __syncthreads();

  const int cg = t & 15;
  const int rg = t >> 4;

  float x2v[8];
  #pragma unroll
  for (int i = 0; i < 8; ++i) x2v[i] = x2s[rg * 8 + i];

  float m1[8]; int i1[8];
  #pragma unroll
  for (int i = 0; i < 8; ++i) { m1[i] = __builtin_inff(); i1[i] = 0x7fffffff; }

  for (int c = 0; c < 4; ++c) {
    __syncthreads();  // protect cbT from overwrite while previous consumers read
    // stage codebook chunk transposed: cbT[d][k]; conflict-free LDS writes
    const float* cbsrc = codebook + c * 128 * DIMS;
    #pragma unroll
    for (int p = 0; p < 8; ++p) {
      int f = p * 256 + t;     // 0..2047
      int d4 = f >> 7;         // 0..15
      int kk = f & 127;        // 0..127
      float4 v = *(const float4*)(cbsrc + kk * DIMS + d4 * 4);
      cbT[(d4 * 4 + 0) * 128 + kk] = v.x;
      cbT[(d4 * 4 + 1) * 128 + kk] = v.y;
      cbT[(d4 * 4 + 2) * 128 + kk] = v.z;
      cbT[(d4 * 4 + 3) * 128 + kk] = v.w;
    }
    __syncthreads();

    float acc[8][8];
    #pragma unroll
    for (int i = 0; i < 8; ++i)
      #pragma unroll
      for (int j = 0; j < 8; ++j) acc[i][j] = 0.f;

    const float* xrow = xt + (rg * 8) * DIMS;
    for (int d4 = 0; d4 < DIMS; d4 += 4) {
      float xv[8][4];
      #pragma unroll
      for (int i = 0; i < 8; ++i)
        *(float4*)&xv[i][0] = *(const float4*)&xrow[i * DIMS + d4];
      #pragma unroll
      for (int dd = 0; dd < 4; ++dd) {  // d strictly ascending: single fmaf chain per (i,j)
        float cv[8];
        *(float4*)&cv[0] = *(const float4*)&cbT[(d4 + dd) * 128 + cg * 8];
        *(float4*)&cv[4] = *(const float4*)&cbT[(d4 + dd) * 128 + cg * 8 + 4];
        #pragma unroll
        for (int i = 0; i < 8; ++i) {
          const float xs = xv[i][dd];
          #pragma unroll
          for (int j = 0; j < 8; ++j) acc[i][j] = fmaf(xs, cv[j], acc[i][j]);
        }
      }
    }

    // d2 = (x2 - 2*M) + c2, each op one fp32 rounding (2*M exact).
    float c2l[8];
    *(float4*)&c2l[0] = *(const float4*)&c2s[c * 128 + cg * 8];
    *(float4*)&c2l[4] = *(const float4*)&c2s[c * 128 + cg * 8 + 4];
    #pragma unroll
    for (int j = 0; j < 8; ++j) {
      const int k = c * 128 + cg * 8 + j;  // ascending k within thread across (c,j)
      const float c2v = c2l[j];
      #pragma unroll
      for (int i = 0; i < 8; ++i) {
        const float tt = x2v[i] - 2.0f * acc[i][j];
        const float s = tt + c2v;
        if (s < m1[i]) { m1[i] = s; i1[i] = k; }  // strict < keeps first index
      }
    }
  }

  // cross-thread merge over cg (16 lanes, contiguous in wave): min value, tie -> min index
  #pragma unroll
  for (int i = 0; i < 8; ++i) {
    float v = m1[i]; int idx = i1[i];
    #pragma unroll
    for (int off = 1; off < 16; off <<= 1) {
      const float ov = __shfl_xor(v, off);
      const int oi = __shfl_xor(idx, off);
      if (ov < v || (ov == v && oi < idx)) { v = ov; idx = oi; }
    }
    if (cg == 0) {
      out_codes[rowbase + rg * 8 + i] = (float)idx;
      atomicAdd(&bins[idx], 1);  // histogram hidden behind compute-bound kernel
    }
  }
}

// ---------------- K2: gather + STE output + per-block loss partial ----------------
// 1024 blocks x 256 threads, grid-stride over 2M float4. NO same-address atomics.
__global__ __launch_bounds__(256) void vq_outputs(const float* __restrict__ latents,
                                                  const float* __restrict__ codebook,
                                                  const float* __restrict__ out_codes,
                                                  float* __restrict__ out_st,
                                                  double* __restrict__ loss_part) {
  #pragma clang fp contract(off)
  const int t = threadIdx.x;
  const int nvec4 = N_ROWS * DIMS / 4;  // 2,097,152
  double acc = 0.0;
  for (int v4 = blockIdx.x * 256 + t; v4 < nvec4; v4 += OUT_BLOCKS * 256) {
    const int row = v4 >> 4;        // 16 float4 per row
    const int dq = v4 & 15;
    const int k = (int)out_codes[row];
    const float4 l = ((const float4*)latents)[v4];
    const float4 q = ((const float4*)codebook)[k * 16 + dq];
    float4 o;
    o.x = l.x + (q.x - l.x);        // straight-through, np rounding order
    o.y = l.y + (q.y - l.y);
    o.z = l.z + (q.z - l.z);
    o.w = l.w + (q.w - l.w);
    ((float4*)out_st)[v4] = o;
    const float dx = l.x - q.x, dy = l.y - q.y, dz = l.z - q.z, dw = l.w - q.w;
    acc += (double)dx * (double)dx;
    acc += (double)dy * (double)dy;
    acc += (double)dz * (double)dz;
    acc += (double)dw * (double)dw;
  }
  // wave reduce then block reduce -> private slot (no atomics)
  #pragma unroll
  for (int off = 32; off > 0; off >>= 1) acc += __shfl_down(acc, off);
  __shared__ double wsum[4];
  if ((t & 63) == 0) wsum[t >> 6] = acc;
  __syncthreads();
  if (t == 0) loss_part[blockIdx.x] = wsum[0] + wsum[1] + wsum[2] + wsum[3];
}

// ---------------- K3: reduce loss partials + perplexity + scalar outputs ----------
__global__ __launch_bounds__(512) void vq_finalize(const int* __restrict__ bins,
                                                   const double* __restrict__ loss_part,
                                                   float* __restrict__ out3) {
  __shared__ double red[512];
  __shared__ double redl[512];
  const int t = threadIdx.x;
  const double p = (double)bins[t] / 131072.0;
  red[t] = -p * log(p + 1e-10);
  redl[t] = loss_part[t] + loss_part[t + 512];
  __syncthreads();
  for (int s = 256; s > 0; s >>= 1) {
    if (t < s) { red[t] += red[t + s]; redl[t] += redl[t + s]; }
    __syncthreads();
  }
  if (t == 0) {
    const double mean = redl[0] / 8388608.0;
    out3[0] = (float)(0.25 * mean);  // commitment * COMMITMENT_COST
    out3[1] = (float)mean;           // codebook_loss (same squares bitwise)
    out3[2] = (float)exp(red[0]);    // perplexity
  }
}

extern "C" void kernel_launch(void* const* d_in, const int* in_sizes, int n_in,
                              void* d_out, int out_size, void* d_ws, size_t ws_size,
                              hipStream_t stream) {
  const float* latents = (const float*)d_in[0];
  const float* codebook = (const float*)d_in[1];

  float* out = (float*)d_out;
  float* out_st = out;                                   // 8388608
  float* out_codes = out + (size_t)N_ROWS * DIMS;        // 131072 (codes as float)
  float* out3 = out_codes + N_ROWS;                      // 3 scalars

  char* ws = (char*)d_ws;
  double* loss_part = (double*)ws;               // [0, 8192)
  int* bins = (int*)(ws + 8192);                 // [8192, 10240)
  float* c2g = (float*)(ws + 10240);             // [10240, 12288)

  hipLaunchKernelGGL(vq_init, dim3(1), dim3(256), 0, stream,
                     codebook, bins, c2g);
  hipLaunchKernelGGL(vq_argmin, dim3(N_ROWS / 128), dim3(256), 0, stream,
                     latents, codebook, c2g, out_codes, bins);
  hipLaunchKernelGGL(vq_outputs, dim3(OUT_BLOCKS), dim3(256), 0, stream,
                     latents, codebook, out_codes, out_st, loss_part);
  hipLaunchKernelGGL(vq_finalize, dim3(1), dim3(512), 0, stream,
                     bins, loss_part, out3);
}